// Round 2
// baseline (130.943 us; speedup 1.0000x reference)
//
#include <hip/hip_runtime.h>
#include <hip/hip_bf16.h>

#define NB 4
#define NN 512
#define ND 128
#define NH 4
#define NK 32

constexpr float EPSV = 1e-6f;
constexpr float CF   = 2.8853900817779268f;   // 2/ln2
constexpr float L2E  = 1.4426950408889634f;   // log2(e)
constexpr float LN2V = 0.6931471805599453f;   // ln(2)

__device__ __forceinline__ float4 ld4(const float* __restrict__ p) {
  return *reinterpret_cast<const float4*>(p);
}

// Kernel 1: x2 + projections ai' = (x@W1a + b1)*CF, aj' = (x@W1b)*CF
// grid = B*N/8 = 256 blocks, 256 threads. thread -> (h, part, k)
__global__ __launch_bounds__(256) void dgf_proj(
    const float* __restrict__ x, const float* __restrict__ W1,
    const float* __restrict__ b1, float* __restrict__ ai2,
    float* __restrict__ aj2, float* __restrict__ x2n) {
  __shared__ float xr[8][ND];
  const int t = threadIdx.x;
  const int blk = blockIdx.x;
  const int b = blk >> 6;
  const int n0 = (blk & 63) << 3;
  const float* xb = x + (size_t)(b * NN + n0) * ND;
  {
    const int row = t >> 5, c = t & 31;
    *reinterpret_cast<float4*>(&xr[row][c * 4]) = ld4(xb + row * ND + c * 4);
  }
  __syncthreads();
  if (t < 8) {
    float s = 0.f;
    for (int d = 0; d < ND; ++d) s = fmaf(xr[t][d], xr[t][d], s);
    x2n[b * NN + n0 + t] = s;
  }
  const int h = t >> 6, part = (t >> 5) & 1, k = t & 31;
  const float* w1p = W1 + (size_t)(h * 256 + part * 128) * NK + k;
  float acc[8] = {0.f, 0.f, 0.f, 0.f, 0.f, 0.f, 0.f, 0.f};
  for (int d = 0; d < ND; d += 4) {
    const float w0 = w1p[(d + 0) * NK];
    const float w1v = w1p[(d + 1) * NK];
    const float w2v = w1p[(d + 2) * NK];
    const float w3v = w1p[(d + 3) * NK];
#pragma unroll
    for (int row = 0; row < 8; ++row) {
      const float4 xv = *reinterpret_cast<const float4*>(&xr[row][d]);
      float a = acc[row];
      a = fmaf(xv.x, w0, a);
      a = fmaf(xv.y, w1v, a);
      a = fmaf(xv.z, w2v, a);
      a = fmaf(xv.w, w3v, a);
      acc[row] = a;
    }
  }
  const float bb = (part == 0) ? b1[h * NK + k] : 0.f;
  float* outp = (part == 0) ? ai2 : aj2;
#pragma unroll
  for (int row = 0; row < 8; ++row) {
    outp[((size_t)(b * NN + n0 + row) * NH + h) * NK + k] = (acc[row] + bb) * CF;
  }
}

// Kernel 2: fused dist/adj/h_out/proj. grid = B*(N/2) = 1024 blocks, 256 threads.
// Block handles (b, i0..i0+1); thread t handles j = t and j = t+256.
__global__ __launch_bounds__(256) void dgf_main(
    const float* __restrict__ x, const float* __restrict__ W2,
    const float* __restrict__ b2, const float* __restrict__ Wp,
    const float* __restrict__ bp, const float* __restrict__ ai2,
    const float* __restrict__ aj2, const float* __restrict__ x2n,
    float* __restrict__ out) {
  __shared__ float4 xi4[2 * 32];     // 2 i-rows of x
  __shared__ float4 ai2s4[2 * 32];   // 2 i-rows of ai' ([r][h*8+kc])
  __shared__ float4 w2s4[32];        // W2 [h][k]
  __shared__ float x2is[2];
  __shared__ float b2s[4];
  __shared__ float2 adjs2[512];      // [j] -> (r0, r1)
  __shared__ float pc[8 * 256];      // [jp][r*128+e]
  __shared__ float hsT[128 * 2];     // [e][r]
  __shared__ float pd[2 * 128 * 2];  // [eh][d][r]
  const int t = threadIdx.x;
  const int blk = blockIdx.x;
  const int b = blk >> 8;
  const int i0 = (blk & 255) << 1;

  // ---- Phase A: stage per-block data ----
  if (t < 64) {
    const int r = t >> 5;
    const int c = t & 31;
    xi4[t]   = ld4(x   + (size_t)(b * NN + i0 + r) * ND + c * 4);
    ai2s4[t] = ld4(ai2 + (size_t)(b * NN + i0 + r) * (NH * NK) + c * 4);
  }
  if (t < 32) w2s4[t] = ld4(W2 + t * 4);
  if (t < 2) x2is[t] = x2n[b * NN + i0 + t];
  if (t < 4) b2s[t] = b2[t];
  __syncthreads();

  // ---- Phase B1: gram dots -> distn = -L2E * dist ----
  float distn0[2], distn1[2];
  {
    float g0[2] = {0.f, 0.f};
    float g1[2] = {0.f, 0.f};
    const float* xj0 = x + (size_t)(b * NN + t) * ND;
    const float* xj1 = xj0 + (size_t)256 * ND;
    for (int c = 0; c < 32; ++c) {
      const float4 a = ld4(xj0 + c * 4);
      const float4 bv = ld4(xj1 + c * 4);
#pragma unroll
      for (int r = 0; r < 2; ++r) {
        const float4 xv = xi4[r * 32 + c];
        float u = g0[r];
        u = fmaf(xv.x, a.x, u); u = fmaf(xv.y, a.y, u);
        u = fmaf(xv.z, a.z, u); u = fmaf(xv.w, a.w, u);
        g0[r] = u;
        float v = g1[r];
        v = fmaf(xv.x, bv.x, v); v = fmaf(xv.y, bv.y, v);
        v = fmaf(xv.z, bv.z, v); v = fmaf(xv.w, bv.w, v);
        g1[r] = v;
      }
    }
    const float x2j0 = x2n[b * NN + t];
    const float x2j1 = x2n[b * NN + t + 256];
#pragma unroll
    for (int r = 0; r < 2; ++r) {
      distn0[r] = -L2E * fmaxf(x2is[r] + x2j0 - 2.f * g0[r], 0.f);
      distn1[r] = -L2E * fmaxf(x2is[r] + x2j1 - 2.f * g1[r], 0.f);
    }
  }

  // ---- Phase B2: heads ----
  float adj0[2] = {0.f, 0.f};
  float adj1[2] = {0.f, 0.f};
#pragma unroll
  for (int jj = 0; jj < 2; ++jj) {
    const float* ajp = aj2 + (size_t)(b * NN + t + jj * 256) * (NH * NK);
    for (int h = 0; h < NH; ++h) {
      float4 aj[8];
#pragma unroll
      for (int c = 0; c < 8; ++c) aj[c] = ld4(ajp + h * NK + c * 4);
      float s[2] = {0.f, 0.f};
#pragma unroll
      for (int kc = 0; kc < 8; ++kc) {
        const float4 w2c = w2s4[h * 8 + kc];
        const float4 ajc = aj[kc];
#pragma unroll
        for (int r = 0; r < 2; ++r) {
          const float4 ac = ai2s4[r * 32 + h * 8 + kc];
          float z, u, tt, sr = s[r];
          z = ac.x + ajc.x; u = __builtin_amdgcn_exp2f(z);
          tt = fmaf(-2.f, __builtin_amdgcn_rcpf(u + 1.f), 1.f);
          sr = fmaf(tt, w2c.x, sr);
          z = ac.y + ajc.y; u = __builtin_amdgcn_exp2f(z);
          tt = fmaf(-2.f, __builtin_amdgcn_rcpf(u + 1.f), 1.f);
          sr = fmaf(tt, w2c.y, sr);
          z = ac.z + ajc.z; u = __builtin_amdgcn_exp2f(z);
          tt = fmaf(-2.f, __builtin_amdgcn_rcpf(u + 1.f), 1.f);
          sr = fmaf(tt, w2c.z, sr);
          z = ac.w + ajc.w; u = __builtin_amdgcn_exp2f(z);
          tt = fmaf(-2.f, __builtin_amdgcn_rcpf(u + 1.f), 1.f);
          sr = fmaf(tt, w2c.w, sr);
          s[r] = sr;
        }
      }
#pragma unroll
      for (int r = 0; r < 2; ++r) {
        const float si = s[r] + b2s[h];
        const float e2 = __builtin_amdgcn_exp2f(si * L2E);
        const float lp = __builtin_amdgcn_logf(e2 + 1.f) * LN2V;
        const float sp = (si > 15.f) ? si : lp;   // softplus
        const float den = fmaf(2.f * sp, sp, EPSV);
        const float rr = __builtin_amdgcn_rcpf(den);
        const float dn = (jj == 0) ? distn0[r] : distn1[r];
        const float term = __builtin_amdgcn_exp2f(dn * rr);
        if (jj == 0) adj0[r] += term; else adj1[r] += term;
      }
    }
  }
  {
    float2 v0, v1;
    v0.x = adj0[0] * 0.25f; v0.y = adj0[1] * 0.25f;
    v1.x = adj1[0] * 0.25f; v1.y = adj1[1] * 0.25f;
    adjs2[t] = v0;
    adjs2[t + 256] = v1;
  }
  __syncthreads();

  // ---- Phase C: h_out = adj @ x ----
  {
    const int dg = t & 31, jp = t >> 5;
    float4 f0 = {0,0,0,0}, f1 = {0,0,0,0};
    const float* xb = x + (size_t)(b * NN) * ND;
    for (int u = 0; u < 64; ++u) {
      const int j = jp * 64 + u;
      const float2 a = adjs2[j];
      const float4 xv = ld4(xb + (size_t)j * ND + dg * 4);
      f0.x = fmaf(a.x, xv.x, f0.x); f0.y = fmaf(a.x, xv.y, f0.y);
      f0.z = fmaf(a.x, xv.z, f0.z); f0.w = fmaf(a.x, xv.w, f0.w);
      f1.x = fmaf(a.y, xv.x, f1.x); f1.y = fmaf(a.y, xv.y, f1.y);
      f1.z = fmaf(a.y, xv.z, f1.z); f1.w = fmaf(a.y, xv.w, f1.w);
    }
    float4* pc4 = reinterpret_cast<float4*>(pc);
    pc4[jp * 64 + 0 * 32 + dg] = f0;
    pc4[jp * 64 + 1 * 32 + dg] = f1;
  }
  __syncthreads();
  // reduce 8 partials -> hsT[e*2+r]
  {
    float v = 0.f;
#pragma unroll
    for (int jp = 0; jp < 8; ++jp) v += pc[jp * 256 + t];
    const int r = t >> 7, e = t & 127;
    hsT[e * 2 + r] = v;
  }
  __syncthreads();

  // ---- Phase D: out = h_out @ Wp + bp ----
  {
    const int d = t & 127, eh = t >> 7;
    float a0 = 0.f, a1 = 0.f;
    for (int ee = 0; ee < 64; ++ee) {
      const int e = eh * 64 + ee;
      const float w = Wp[(size_t)e * ND + d];
      a0 = fmaf(hsT[e * 2 + 0], w, a0);
      a1 = fmaf(hsT[e * 2 + 1], w, a1);
    }
    pd[(eh * 128 + d) * 2 + 0] = a0;
    pd[(eh * 128 + d) * 2 + 1] = a1;
  }
  __syncthreads();
  {
    const int r = t >> 7, d = t & 127;
    const float v = pd[d * 2 + r] + pd[(128 + d) * 2 + r] + bp[d];
    out[(size_t)(b * NN + i0 + r) * ND + d] = v;
  }
}

extern "C" void kernel_launch(void* const* d_in, const int* in_sizes, int n_in,
                              void* d_out, int out_size, void* d_ws, size_t ws_size,
                              hipStream_t stream) {
  const float* x  = (const float*)d_in[0];
  const float* W1 = (const float*)d_in[1];
  const float* b1 = (const float*)d_in[2];
  const float* W2 = (const float*)d_in[3];
  const float* b2 = (const float*)d_in[4];
  const float* Wp = (const float*)d_in[5];
  const float* bp = (const float*)d_in[6];
  float* out = (float*)d_out;

  float* aj2 = (float*)d_ws;                       // B*N*H*NK floats
  float* ai2 = aj2 + (size_t)NB * NN * NH * NK;    // B*N*H*NK floats
  float* x2n = ai2 + (size_t)NB * NN * NH * NK;    // B*N floats

  dgf_proj<<<NB * NN / 8, 256, 0, stream>>>(x, W1, b1, ai2, aj2, x2n);
  dgf_main<<<NB * (NN / 2), 256, 0, stream>>>(x, W2, b2, Wp, bp, ai2, aj2, x2n, out);
}

// Round 3
// 59.083 us; speedup vs baseline: 2.2163x; 2.2163x over previous
//
#include <hip/hip_runtime.h>
#include <hip/hip_bf16.h>

#define NB 4
#define NN 512
#define ND 128
#define NH 4
#define NK 32

constexpr float EPSV = 1e-6f;
constexpr float CF   = 2.8853900817779268f;   // 2/ln2
constexpr float L2E  = 1.4426950408889634f;   // log2(e)
constexpr float LN2V = 0.6931471805599453f;   // ln(2)

__device__ __forceinline__ float4 ld4(const float* __restrict__ p) {
  return *reinterpret_cast<const float4*>(p);
}

// Kernel 1: x2 + projections ai' = (x@W1a + b1)*CF, aj' = (x@W1b)*CF
// grid = B*N/8 = 256 blocks, 256 threads. thread -> (h, part, k)
__global__ __launch_bounds__(256) void dgf_proj(
    const float* __restrict__ x, const float* __restrict__ W1,
    const float* __restrict__ b1, float* __restrict__ ai2,
    float* __restrict__ aj2, float* __restrict__ x2n) {
  __shared__ float xr[8][ND];
  const int t = threadIdx.x;
  const int blk = blockIdx.x;
  const int b = blk >> 6;
  const int n0 = (blk & 63) << 3;
  const float* xb = x + (size_t)(b * NN + n0) * ND;
  {
    const int row = t >> 5, c = t & 31;
    *reinterpret_cast<float4*>(&xr[row][c * 4]) = ld4(xb + row * ND + c * 4);
  }
  __syncthreads();
  if (t < 8) {
    float s = 0.f;
    for (int d = 0; d < ND; ++d) s = fmaf(xr[t][d], xr[t][d], s);
    x2n[b * NN + n0 + t] = s;
  }
  const int h = t >> 6, part = (t >> 5) & 1, k = t & 31;
  const float* w1p = W1 + (size_t)(h * 256 + part * 128) * NK + k;
  float acc[8] = {0.f, 0.f, 0.f, 0.f, 0.f, 0.f, 0.f, 0.f};
  for (int d = 0; d < ND; d += 4) {
    const float w0 = w1p[(d + 0) * NK];
    const float w1v = w1p[(d + 1) * NK];
    const float w2v = w1p[(d + 2) * NK];
    const float w3v = w1p[(d + 3) * NK];
#pragma unroll
    for (int row = 0; row < 8; ++row) {
      const float4 xv = *reinterpret_cast<const float4*>(&xr[row][d]);
      float a = acc[row];
      a = fmaf(xv.x, w0, a);
      a = fmaf(xv.y, w1v, a);
      a = fmaf(xv.z, w2v, a);
      a = fmaf(xv.w, w3v, a);
      acc[row] = a;
    }
  }
  const float bb = (part == 0) ? b1[h * NK + k] : 0.f;
  float* outp = (part == 0) ? ai2 : aj2;
#pragma unroll
  for (int row = 0; row < 8; ++row) {
    outp[((size_t)(b * NN + n0 + row) * NH + h) * NK + k] = (acc[row] + bb) * CF;
  }
}

// Kernel 2: fused dist/adj/h_out/proj. grid = B*(N/4) = 512 blocks, 512 threads.
// Block handles (b, i0..i0+3); thread t handles j = t.
__global__ __launch_bounds__(512, 4) void dgf_main(
    const float* __restrict__ x, const float* __restrict__ W2,
    const float* __restrict__ b2, const float* __restrict__ Wp,
    const float* __restrict__ bp, const float* __restrict__ ai2,
    const float* __restrict__ aj2, const float* __restrict__ x2n,
    float* __restrict__ out) {
  __shared__ float4 xi4[4 * 32];     // 4 i-rows of x
  __shared__ float4 ai2s4[4 * 32];   // 4 i-rows of ai' ([r][h*8+kc])
  __shared__ float4 w2s4[32];        // W2 [h][k]
  __shared__ float x2is[4];
  __shared__ float b2s[4];
  __shared__ float4 adjs4[512];      // [j] -> (r0..r3)  8KB
  __shared__ float pcbuf[16 * 512];  // 32KB: phase C partials; reused as pd in D
  __shared__ float hsT[4 * 128];     // [r][e]  2KB
  const int t = threadIdx.x;
  const int blk = blockIdx.x;
  const int b = blk >> 7;
  const int i0 = (blk & 127) << 2;

  // ---- Phase A: stage per-block data ----
  if (t < 128) {
    const int r = t >> 5;
    const int c = t & 31;
    xi4[t]   = ld4(x   + (size_t)(b * NN + i0 + r) * ND + c * 4);
    ai2s4[t] = ld4(ai2 + (size_t)(b * NN + i0 + r) * (NH * NK) + c * 4);
  } else if (t < 160) {
    w2s4[t - 128] = ld4(W2 + (t - 128) * 4);
  } else if (t < 164) {
    x2is[t - 160] = x2n[b * NN + i0 + (t - 160)];
  } else if (t < 168) {
    b2s[t - 164] = b2[t - 164];
  }
  __syncthreads();

  // ---- Phase B1: gram dots -> distn = -L2E * dist ----
  float distn[4];
  {
    float g[4] = {0.f, 0.f, 0.f, 0.f};
    const float* xj = x + (size_t)(b * NN + t) * ND;
    for (int c = 0; c < 32; ++c) {
      const float4 a = ld4(xj + c * 4);
#pragma unroll
      for (int r = 0; r < 4; ++r) {
        const float4 xv = xi4[r * 32 + c];
        float u = g[r];
        u = fmaf(xv.x, a.x, u); u = fmaf(xv.y, a.y, u);
        u = fmaf(xv.z, a.z, u); u = fmaf(xv.w, a.w, u);
        g[r] = u;
      }
    }
    const float x2j = x2n[b * NN + t];
#pragma unroll
    for (int r = 0; r < 4; ++r) {
      distn[r] = -L2E * fmaxf(x2is[r] + x2j - 2.f * g[r], 0.f);
    }
  }

  // ---- Phase B2: heads ----
  float adjv[4] = {0.f, 0.f, 0.f, 0.f};
  {
    const float* ajp = aj2 + (size_t)(b * NN + t) * (NH * NK);
    for (int h = 0; h < NH; ++h) {
      float4 aj[8];
#pragma unroll
      for (int c = 0; c < 8; ++c) aj[c] = ld4(ajp + h * NK + c * 4);
      float s[4] = {0.f, 0.f, 0.f, 0.f};
#pragma unroll
      for (int kc = 0; kc < 8; ++kc) {
        const float4 w2c = w2s4[h * 8 + kc];
        const float4 ajc = aj[kc];
#pragma unroll
        for (int r = 0; r < 4; ++r) {
          const float4 ac = ai2s4[r * 32 + h * 8 + kc];
          float z, u, tt, sr = s[r];
          z = ac.x + ajc.x; u = __builtin_amdgcn_exp2f(z);
          tt = fmaf(-2.f, __builtin_amdgcn_rcpf(u + 1.f), 1.f);
          sr = fmaf(tt, w2c.x, sr);
          z = ac.y + ajc.y; u = __builtin_amdgcn_exp2f(z);
          tt = fmaf(-2.f, __builtin_amdgcn_rcpf(u + 1.f), 1.f);
          sr = fmaf(tt, w2c.y, sr);
          z = ac.z + ajc.z; u = __builtin_amdgcn_exp2f(z);
          tt = fmaf(-2.f, __builtin_amdgcn_rcpf(u + 1.f), 1.f);
          sr = fmaf(tt, w2c.z, sr);
          z = ac.w + ajc.w; u = __builtin_amdgcn_exp2f(z);
          tt = fmaf(-2.f, __builtin_amdgcn_rcpf(u + 1.f), 1.f);
          sr = fmaf(tt, w2c.w, sr);
          s[r] = sr;
        }
      }
#pragma unroll
      for (int r = 0; r < 4; ++r) {
        const float si = s[r] + b2s[h];
        const float e2 = __builtin_amdgcn_exp2f(si * L2E);
        const float lp = __builtin_amdgcn_logf(e2 + 1.f) * LN2V;
        const float sp = (si > 15.f) ? si : lp;   // softplus
        const float den = fmaf(2.f * sp, sp, EPSV);
        const float rr = __builtin_amdgcn_rcpf(den);
        const float term = __builtin_amdgcn_exp2f(distn[r] * rr);
        adjv[r] += term;
      }
    }
  }
  {
    float4 v;
    v.x = adjv[0] * 0.25f; v.y = adjv[1] * 0.25f;
    v.z = adjv[2] * 0.25f; v.w = adjv[3] * 0.25f;
    adjs4[t] = v;
  }
  __syncthreads();

  // ---- Phase C: h_out = adj @ x ----
  {
    const int dg = t & 31, jp = t >> 5;   // 16 j-groups of 32 j's
    float4 f0 = {0,0,0,0}, f1 = {0,0,0,0}, f2 = {0,0,0,0}, f3 = {0,0,0,0};
    const float* xb = x + (size_t)(b * NN) * ND;
    for (int u = 0; u < 32; ++u) {
      const int j = jp * 32 + u;
      const float4 a = adjs4[j];
      const float4 xv = ld4(xb + (size_t)j * ND + dg * 4);
      f0.x = fmaf(a.x, xv.x, f0.x); f0.y = fmaf(a.x, xv.y, f0.y);
      f0.z = fmaf(a.x, xv.z, f0.z); f0.w = fmaf(a.x, xv.w, f0.w);
      f1.x = fmaf(a.y, xv.x, f1.x); f1.y = fmaf(a.y, xv.y, f1.y);
      f1.z = fmaf(a.y, xv.z, f1.z); f1.w = fmaf(a.y, xv.w, f1.w);
      f2.x = fmaf(a.z, xv.x, f2.x); f2.y = fmaf(a.z, xv.y, f2.y);
      f2.z = fmaf(a.z, xv.z, f2.z); f2.w = fmaf(a.z, xv.w, f2.w);
      f3.x = fmaf(a.w, xv.x, f3.x); f3.y = fmaf(a.w, xv.y, f3.y);
      f3.z = fmaf(a.w, xv.z, f3.z); f3.w = fmaf(a.w, xv.w, f3.w);
    }
    float4* pc4 = reinterpret_cast<float4*>(pcbuf);
    pc4[jp * 128 + 0 * 32 + dg] = f0;
    pc4[jp * 128 + 1 * 32 + dg] = f1;
    pc4[jp * 128 + 2 * 32 + dg] = f2;
    pc4[jp * 128 + 3 * 32 + dg] = f3;
  }
  __syncthreads();
  // reduce 16 partials -> hsT[r*128+e]
  {
    float v = 0.f;
#pragma unroll
    for (int jp = 0; jp < 16; ++jp) v += pcbuf[jp * 512 + t];
    hsT[t] = v;   // t = r*128 + e
  }
  __syncthreads();

  // ---- Phase D: out = h_out @ Wp + bp ----
  {
    const int d = t & 127, eh = t >> 7;   // 4 e-groups of 32 e's
    float a0 = 0.f, a1 = 0.f, a2 = 0.f, a3 = 0.f;
    for (int ee = 0; ee < 32; ++ee) {
      const int e = eh * 32 + ee;
      const float w = Wp[(size_t)e * ND + d];
      a0 = fmaf(hsT[0 * 128 + e], w, a0);
      a1 = fmaf(hsT[1 * 128 + e], w, a1);
      a2 = fmaf(hsT[2 * 128 + e], w, a2);
      a3 = fmaf(hsT[3 * 128 + e], w, a3);
    }
    float* pd = pcbuf;   // reuse (safe: one barrier since last pcbuf read)
    pd[eh * 512 + 0 * 128 + d] = a0;
    pd[eh * 512 + 1 * 128 + d] = a1;
    pd[eh * 512 + 2 * 128 + d] = a2;
    pd[eh * 512 + 3 * 128 + d] = a3;
  }
  __syncthreads();
  {
    const float* pd = pcbuf;
    const int r = t >> 7, d = t & 127;
    const float v = pd[0 * 512 + t] + pd[1 * 512 + t] + pd[2 * 512 + t] +
                    pd[3 * 512 + t] + bp[d];
    out[(size_t)(b * NN + i0 + r) * ND + d] = v;
  }
}

extern "C" void kernel_launch(void* const* d_in, const int* in_sizes, int n_in,
                              void* d_out, int out_size, void* d_ws, size_t ws_size,
                              hipStream_t stream) {
  const float* x  = (const float*)d_in[0];
  const float* W1 = (const float*)d_in[1];
  const float* b1 = (const float*)d_in[2];
  const float* W2 = (const float*)d_in[3];
  const float* b2 = (const float*)d_in[4];
  const float* Wp = (const float*)d_in[5];
  const float* bp = (const float*)d_in[6];
  float* out = (float*)d_out;

  float* aj2 = (float*)d_ws;                       // B*N*H*NK floats
  float* ai2 = aj2 + (size_t)NB * NN * NH * NK;    // B*N*H*NK floats
  float* x2n = ai2 + (size_t)NB * NN * NH * NK;    // B*N floats

  dgf_proj<<<NB * NN / 8, 256, 0, stream>>>(x, W1, b1, ai2, aj2, x2n);
  dgf_main<<<NB * (NN / 4), 512, 0, stream>>>(x, W2, b2, Wp, bp, ai2, aj2, x2n, out);
}